// Round 10
// baseline (377.469 us; speedup 1.0000x reference)
//
#include <hip/hip_runtime.h>
#include <cmath>

typedef _Float16 f16;
typedef _Float16 f16x2 __attribute__((ext_vector_type(2)));
typedef _Float16 f16x4 __attribute__((ext_vector_type(4)));
typedef _Float16 f16x8 __attribute__((ext_vector_type(8)));
typedef float f32x4 __attribute__((ext_vector_type(4)));

namespace {

constexpr int kB = 8;
constexpr int kL = 680;
constexpr int kH = 24;
constexpr int kD = 64;
constexpr int kC = 1536;          // kH * kD
constexpr int kM = kB * kL;       // 5440
constexpr int kN3 = 3 * kC;       // 4608
constexpr int kNKT = 11;          // ceil(680/64)
constexpr int kNQT = 6;           // ceil(680/128)

#define ASYNC_CP16(gp, lp)                                          \
  __builtin_amdgcn_global_load_lds(                                 \
      (const __attribute__((address_space(1))) unsigned int*)(gp),  \
      (__attribute__((address_space(3))) unsigned int*)(lp), 16, 0, 0)

// Bijective XCD swizzle (m204).
__device__ inline int xcd_swizzle(int bid, int nwg) {
  int q = nwg >> 3, r = nwg & 7;
  int x = bid & 7, idx = bid >> 3;
  return (x < r ? x * (q + 1) : r * (q + 1) + (x - r) * q) + idx;
}

// 4-wide n-stripe decode (with xcd_swizzle: FETCH 122.9 -> 74.3 MB, r6).
__device__ inline void stripe_decode(int id, int gx, int gy, int& mt,
                                     int& nt) {
  const int SW = 4;
  int nst = (gx + SW - 1) / SW;
  int s = id / (gy * SW);
  if (s > nst - 1) s = nst - 1;
  int rem = id - s * gy * SW;
  int w = gx - s * SW;
  if (w > SW) w = SW;
  mt = rem / w;
  nt = s * SW + rem % w;
}

// ------------------------- fused fp32->fp16 conversions + bias build
__global__ void fused_cvt_bias(const float* __restrict__ x,
                               const float* __restrict__ wqkv,
                               const float* __restrict__ wo,
                               const float* __restrict__ qb,
                               const float* __restrict__ vb,
                               f16* __restrict__ x16,
                               f16* __restrict__ wqkv16,
                               f16* __restrict__ wo16,
                               float* __restrict__ bias) {
  const int c0 = kM * kC / 4, c1 = kN3 * kC / 4, c2 = kC * kC / 4,
            c3 = kN3 / 4;
  int i = blockIdx.x * blockDim.x + threadIdx.x;
  const float* src = nullptr;
  f16* dst = nullptr;
  if (i < c0) {
    src = x; dst = x16;
  } else if ((i -= c0) < c1) {
    src = wqkv; dst = wqkv16;
  } else if ((i -= c1) < c2) {
    src = wo; dst = wo16;
  } else if ((i -= c2) < c3) {
    int base = i * 4;
    float vv[4];
#pragma unroll
    for (int k2 = 0; k2 < 4; ++k2) {
      int idx = base + k2;
      float b = 0.0f;
      if (idx < kC) b = qb[idx];
      else if (idx >= 2 * kC) b = vb[idx - 2 * kC];
      vv[k2] = b;
    }
    *reinterpret_cast<float4*>(&bias[base]) =
        make_float4(vv[0], vv[1], vv[2], vv[3]);
    return;
  } else {
    return;
  }
  float4 v = *reinterpret_cast<const float4*>(&src[i * 4]);
  f16x4 o;
  o[0] = (f16)v.x; o[1] = (f16)v.y; o[2] = (f16)v.z; o[3] = (f16)v.w;
  *reinterpret_cast<f16x4*>(&dst[i * 4]) = o;
}

// ----------------------------------- v14: v10's verified 8-phase GEMM
// (143.4us QKV, MfmaUtil 22.7, conflicts 0). r9 diagnostic split reverted
// (cost +11us; it established attn < 76.2us and proj < 76.2us -- no hidden
// monster dispatch). Per-block time ~72-77us for 24 tiles regardless of
// grid size: the GEMM is per-block-latency-pinned (local optimum; 4-phase
// merge and tri-buffer variants both falsified).
template <typename OutT, bool ROPE>
__global__ __launch_bounds__(512, 2) void gemm256_8ph(
    const f16* __restrict__ A, const f16* __restrict__ Bw,
    const float* __restrict__ bias, OutT* __restrict__ Cm,
    const float* __restrict__ pos, int M, int N, int K, int n_base) {
  constexpr int HALF = 8192;      // f16 per half-tile (128 rows x 64 k)
  constexpr int ABUF = 2 * HALF;  // 16384 f16
  constexpr int BUF = 2 * ABUF;   // 32768 f16: [A h0|A h1|B h0|B h1]
  __shared__ __align__(16) f16 sm[2 * BUF];  // 128 KB

  const int tid = threadIdx.x;
  const int w = tid >> 6;
  const int lane = tid & 63;
  const int lr = lane & 15;
  const int quad = lane >> 4;
  const int wr = w >> 2;   // 0..1 : which 128-row half this wave computes
  const int wc = w & 3;    // 0..3 : which 64-col quarter
  const int gx = gridDim.x;
  const int sw = xcd_swizzle(blockIdx.y * gx + blockIdx.x, gx * gridDim.y);
  int mt, nt;
  stripe_decode(sw, gx, gridDim.y, mt, nt);
  const int m0 = mt * 256;
  const int n0 = n_base + nt * 256;
  const int NT = K >> 6;   // 24 (even)

  // Staging descriptors. Each half-tile = 1024 16B-blocks; thread covers
  // block idx = tid and tid+512. idx -> kb = idx>>7 (k-group), r = idx&127.
  const f16* aptr[2][2];  // [half][n]
  const f16* bptr[2][2];
  int dstoff0 = tid * 8;
  int dstoff1 = (tid + 512) * 8;
#pragma unroll
  for (int h = 0; h < 2; ++h) {
#pragma unroll
    for (int n = 0; n < 2; ++n) {
      int idx = n * 512 + tid;
      int kb = idx >> 7, r = idx & 127;
      int ra = m0 + h * 128 + r;
      if (ra > M - 1) ra = M - 1;  // duplicate last rows; stores masked
      aptr[h][n] = A + (size_t)ra * K + kb * 8;
      bptr[h][n] = Bw + (size_t)(n0 + h * 128 + r) * K + kb * 8;  // N%256==0
    }
  }

  auto stageA = [&](int t, int h, int q) {
    f16* d = &sm[q * BUF + h * HALF];
    ASYNC_CP16(aptr[h][0] + t * 64, &d[dstoff0]);
    ASYNC_CP16(aptr[h][1] + t * 64, &d[dstoff1]);
  };
  auto stageB = [&](int t, int h, int q) {
    f16* d = &sm[q * BUF + ABUF + h * HALF];
    ASYNC_CP16(bptr[h][0] + t * 64, &d[dstoff0]);
    ASYNC_CP16(bptr[h][1] + t * 64, &d[dstoff1]);
  };

  f32x4 acc[8][4];
#pragma unroll
  for (int i = 0; i < 8; ++i)
#pragma unroll
    for (int j = 0; j < 4; ++j)
#pragma unroll
      for (int c = 0; c < 4; ++c) acc[i][j][c] = 0.0f;

  const int bRow0 = (wc & 1) * 64;  // col offset within B half-tile

  // Prologue: tile0 (4 halves) + B(1) halves = 12 loads; vmcnt(4) leaves
  // B(1)'s 4 in flight and guarantees tile0 landed. A(1) comes at P1/P2.
  stageA(0, 0, 0);
  stageA(0, 1, 0);
  stageB(0, 0, 0);
  stageB(0, 1, 0);
  stageB(1, 0, 1);
  stageB(1, 1, 1);
  asm volatile("s_waitcnt vmcnt(4)" ::: "memory");
  __builtin_amdgcn_s_barrier();

  const int NIT = NT >> 1;
  for (int itr = 0; itr < NIT; ++itr) {
    const int t0 = itr * 2;
#pragma unroll
    for (int hf = 0; hf < 2; ++hf) {
      const int tcur = t0 + hf;      // consumed tile, buffer = hf
      const int ta = tcur + 1;       // A prefetch target -> buf hf^1
      const int tb = tcur + 2;       // B prefetch target -> buf hf
      const f16* Aq = &sm[hf * BUF + wr * HALF];
      const f16* Bq = &sm[hf * BUF + ABUF + (wc >> 1) * HALF];
      f16x8 a0[4], a1[4], b0[4], b1[4];

      // ---- P1 (8 reads): A s0 i0-3 + B s0 j0-3; stage Ah0(ta)
#pragma unroll
      for (int i = 0; i < 4; ++i)
        a0[i] = *reinterpret_cast<const f16x8*>(
            &Aq[((quad << 7) + i * 16 + lr) * 8]);
#pragma unroll
      for (int j = 0; j < 4; ++j)
        b0[j] = *reinterpret_cast<const f16x8*>(
            &Bq[((quad << 7) + bRow0 + j * 16 + lr) * 8]);
      if (ta < NT) stageA(ta, 0, hf ^ 1);
      __builtin_amdgcn_s_barrier();
      asm volatile("s_waitcnt lgkmcnt(0)" ::: "memory");
      __builtin_amdgcn_s_setprio(1);
#pragma unroll
      for (int i = 0; i < 4; ++i)
#pragma unroll
        for (int j = 0; j < 4; ++j)
          acc[i][j] = __builtin_amdgcn_mfma_f32_16x16x32_f16(
              a0[i], b0[j], acc[i][j], 0, 0, 0);
      __builtin_amdgcn_s_setprio(0);
      __builtin_amdgcn_s_barrier();

      // ---- P2 (8 reads): B s1 j0-3 + A s0 i4-7; stage Ah1(ta)
#pragma unroll
      for (int j = 0; j < 4; ++j)
        b1[j] = *reinterpret_cast<const f16x8*>(
            &Bq[(((4 + quad) << 7) + bRow0 + j * 16 + lr) * 8]);
#pragma unroll
      for (int i = 0; i < 4; ++i)
        a1[i] = *reinterpret_cast<const f16x8*>(
            &Aq[((quad << 7) + (i + 4) * 16 + lr) * 8]);
      if (ta < NT) stageA(ta, 1, hf ^ 1);
      __builtin_amdgcn_s_barrier();
      asm volatile("s_waitcnt lgkmcnt(0)" ::: "memory");
      __builtin_amdgcn_s_setprio(1);
#pragma unroll
      for (int i = 0; i < 4; ++i)
#pragma unroll
        for (int j = 0; j < 4; ++j)
          acc[i + 4][j] = __builtin_amdgcn_mfma_f32_16x16x32_f16(
              a1[i], b0[j], acc[i + 4][j], 0, 0, 0);
      __builtin_amdgcn_s_setprio(0);
      __builtin_amdgcn_s_barrier();

      // ---- P3 (4 reads): A s1 i0-3; stage Bh0(tb)
#pragma unroll
      for (int i = 0; i < 4; ++i)
        a0[i] = *reinterpret_cast<const f16x8*>(
            &Aq[(((4 + quad) << 7) + i * 16 + lr) * 8]);
      if (tb < NT) stageB(tb, 0, hf);
      __builtin_amdgcn_s_barrier();
      asm volatile("s_waitcnt lgkmcnt(0)" ::: "memory");
      __builtin_amdgcn_s_setprio(1);
#pragma unroll
      for (int i = 0; i < 4; ++i)
#pragma unroll
        for (int j = 0; j < 4; ++j)
          acc[i][j] = __builtin_amdgcn_mfma_f32_16x16x32_f16(
              a0[i], b1[j], acc[i][j], 0, 0, 0);
      __builtin_amdgcn_s_setprio(0);
      __builtin_amdgcn_s_barrier();

      // ---- P4 (4 reads): A s1 i4-7; stage Bh1(tb); gate
#pragma unroll
      for (int i = 0; i < 4; ++i)
        a1[i] = *reinterpret_cast<const f16x8*>(
            &Aq[(((4 + quad) << 7) + (i + 4) * 16 + lr) * 8]);
      if (tb < NT) stageB(tb, 1, hf);
      __builtin_amdgcn_s_barrier();
      asm volatile("s_waitcnt lgkmcnt(0)" ::: "memory");
      __builtin_amdgcn_s_setprio(1);
#pragma unroll
      for (int i = 0; i < 4; ++i)
#pragma unroll
        for (int j = 0; j < 4; ++j)
          acc[i + 4][j] = __builtin_amdgcn_mfma_f32_16x16x32_f16(
              a1[i], b1[j], acc[i + 4][j], 0, 0, 0);
      __builtin_amdgcn_s_setprio(0);
      if (tb < NT)
        asm volatile("s_waitcnt vmcnt(4)" ::: "memory");
      else
        asm volatile("s_waitcnt vmcnt(0)" ::: "memory");
      __builtin_amdgcn_s_barrier();
    }
  }

  // Epilogue: C/D layout col = lane&15, row = quad*4+reg.
  float bv[4];
#pragma unroll
  for (int j = 0; j < 4; ++j) bv[j] = bias[n0 + wc * 64 + j * 16 + lr];

  if (ROPE && n0 < 2 * kC) {
    // 2D RoPE on a Q or K block (native __sinf/__cosf: no scratch, r5 fix).
    const float fr = exp2f(-(float)lr * (13.287712379549449f / 16.0f));
#pragma unroll
    for (int i = 0; i < 8; ++i) {
#pragma unroll
      for (int r = 0; r < 4; ++r) {
        int row = m0 + wr * 128 + i * 16 + quad * 4 + r;
        if (row < M) {
          float a0r = pos[row * 2 + 0] * fr;
          float a1r = pos[row * 2 + 1] * fr;
          float s0 = __sinf(a0r), c0 = __cosf(a0r);
          float s1 = __sinf(a1r), c1 = __cosf(a1r);
#pragma unroll
          for (int j = 0; j < 2; ++j) {
            float v0 = acc[i][j][r] + bv[j];
            float v1 = acc[i][j + 2][r] + bv[j + 2];
            int col = n0 + wc * 64 + j * 16 + lr;
            Cm[(size_t)row * N + col] = (OutT)(v0 * c0 - v1 * s0);
            Cm[(size_t)row * N + col + 32] = (OutT)(v1 * c1 + v0 * s1);
          }
        }
      }
    }
  } else {
#pragma unroll
    for (int i = 0; i < 8; ++i) {
#pragma unroll
      for (int j = 0; j < 4; ++j) {
#pragma unroll
        for (int r = 0; r < 4; ++r) {
          int row = m0 + wr * 128 + i * 16 + quad * 4 + r;
          if (row < M) {
            int col = n0 + wc * 64 + j * 16 + lr;
            Cm[(size_t)row * N + col] = (OutT)(acc[i][j][r] + bv[j]);
          }
        }
      }
    }
  }
}

// ----------------------------------------------------- MFMA flash attention
// v14 changes (attn was never in top-5 => < 76.2us, est 65-75us, the
// largest never-optimized consumer):
//  - __launch_bounds__(256, 4): 3 -> 4 blocks/CU (LDS 36KB x 4 = 144 <= 160;
//    VGPR estimate ~124 <= 128). attn's serial QK^T->exp->P->PV chain is
//    latency-bound per wave; TLP is the hiding mechanism (+33% waves).
//    If this spills, total regresses and next round reverts + restructures.
//  - 1/8 softmax scale folded into Q at load (power-of-2 f16 exponent
//    shift: exact, distributes exactly through MFMA accumulation) --
//    deletes 352 dependent-path VALU muls per block.
__global__ __launch_bounds__(256, 4) void attn_mfma(
    const f16* __restrict__ qkv, f16* __restrict__ attnout) {
  __shared__ __align__(16) f16 Ks[64 * 72];       // [key][d]
  __shared__ __align__(16) f16 Vts[64 * 72];      // [d][key]  (V transposed)
  __shared__ __align__(16) f16 Pl[4][32 * 72];    // per-wave [qrow][key] f16

  const int tid = threadIdx.x;
  const int w = tid >> 6;
  const int lane = tid & 63;
  const int lr = lane & 15;
  const int qd = lane >> 4;

  const int bid = blockIdx.x;
  const int xcd = bid & 7;
  const int rest = bid >> 3;
  const int qt = rest % kNQT;
  const int g = xcd + 8 * (rest / kNQT);
  const int h = g % kH;
  const int b = g / kH;
  const int q0 = qt * 128;

  f16x8 aq[2][2];
#pragma unroll
  for (int rt = 0; rt < 2; ++rt) {
    int qrow = q0 + w * 32 + rt * 16 + lr;
    if (qrow > kL - 1) qrow = kL - 1;
    const f16* qp = qkv + (size_t)(b * kL + qrow) * kN3 + h * kD;
#pragma unroll
    for (int ks = 0; ks < 2; ++ks) {
      f16x8 qv = *reinterpret_cast<const f16x8*>(qp + ks * 32 + qd * 8);
#pragma unroll
      for (int e = 0; e < 8; ++e) qv[e] = qv[e] * (f16)0.125f;
      aq[rt][ks] = qv;
    }
  }

  const int kkey0 = tid >> 3, kdc = tid & 7;
  const int kkey1 = (tid + 256) >> 3;
  const int vkey0 = (tid & 31) * 2;
  const int vd0 = (tid >> 5) * 8;

  f16x8 kpre0, kpre1, vpre0, vpre1;
  auto prefetch = [&](int kt0) {
    int kg0 = kt0 + kkey0;
    if (kg0 > kL - 1) kg0 = kL - 1;
    kpre0 = *reinterpret_cast<const f16x8*>(
        qkv + (size_t)(b * kL + kg0) * kN3 + kC + h * kD + kdc * 8);
    int kg1 = kt0 + kkey1;
    if (kg1 > kL - 1) kg1 = kL - 1;
    kpre1 = *reinterpret_cast<const f16x8*>(
        qkv + (size_t)(b * kL + kg1) * kN3 + kC + h * kD + kdc * 8);
    int vg0 = kt0 + vkey0;
    if (vg0 > kL - 1) vg0 = kL - 1;
    vpre0 = *reinterpret_cast<const f16x8*>(
        qkv + (size_t)(b * kL + vg0) * kN3 + 2 * kC + h * kD + vd0);
    int vg1 = kt0 + vkey0 + 1;
    if (vg1 > kL - 1) vg1 = kL - 1;
    vpre1 = *reinterpret_cast<const f16x8*>(
        qkv + (size_t)(b * kL + vg1) * kN3 + 2 * kC + h * kD + vd0);
  };
  prefetch(0);

  f32x4 o_acc[2][4];
#pragma unroll
  for (int rt = 0; rt < 2; ++rt)
#pragma unroll
    for (int nt = 0; nt < 4; ++nt)
#pragma unroll
      for (int r = 0; r < 4; ++r) o_acc[rt][nt][r] = 0.0f;
  float lsum[2][4] = {{0.f, 0.f, 0.f, 0.f}, {0.f, 0.f, 0.f, 0.f}};

  for (int it = 0; it < kNKT; ++it) {
    const int kt0 = it * 64;
    __syncthreads();

    *reinterpret_cast<f16x8*>(&Ks[kkey0 * 72 + kdc * 8]) = kpre0;
    *reinterpret_cast<f16x8*>(&Ks[kkey1 * 72 + kdc * 8]) = kpre1;
#pragma unroll
    for (int i = 0; i < 8; ++i) {
      f16x2 pr;
      pr[0] = vpre0[i];
      pr[1] = vpre1[i];
      *reinterpret_cast<f16x2*>(&Vts[(vd0 + i) * 72 + vkey0]) = pr;
    }
    prefetch((it < kNKT - 1) ? (it + 1) * 64 : it * 64);
    __syncthreads();

    f32x4 s_acc[2][4];
#pragma unroll
    for (int rt = 0; rt < 2; ++rt)
#pragma unroll
      for (int t = 0; t < 4; ++t)
#pragma unroll
        for (int r = 0; r < 4; ++r) s_acc[rt][t][r] = 0.0f;
#pragma unroll
    for (int ks = 0; ks < 2; ++ks) {
#pragma unroll
      for (int t = 0; t < 4; ++t) {
        f16x8 bk = *reinterpret_cast<const f16x8*>(
            &Ks[(t * 16 + lr) * 72 + ks * 32 + qd * 8]);
        s_acc[0][t] = __builtin_amdgcn_mfma_f32_16x16x32_f16(
            aq[0][ks], bk, s_acc[0][t], 0, 0, 0);
        s_acc[1][t] = __builtin_amdgcn_mfma_f32_16x16x32_f16(
            aq[1][ks], bk, s_acc[1][t], 0, 0, 0);
      }
    }

#pragma unroll
    for (int rt = 0; rt < 2; ++rt) {
#pragma unroll
      for (int t = 0; t < 4; ++t) {
        const bool valid = (kt0 + t * 16 + lr) < kL;
#pragma unroll
        for (int r = 0; r < 4; ++r) {
          float p = valid ? __expf(s_acc[rt][t][r]) : 0.0f;
          lsum[rt][r] += p;
          Pl[w][(rt * 16 + qd * 4 + r) * 72 + t * 16 + lr] = (f16)p;
        }
      }
    }

#pragma unroll
    for (int ks = 0; ks < 2; ++ks) {
      f16x8 ap[2];
#pragma unroll
      for (int rt = 0; rt < 2; ++rt)
        ap[rt] = *reinterpret_cast<const f16x8*>(
            &Pl[w][(rt * 16 + lr) * 72 + ks * 32 + qd * 8]);
#pragma unroll
      for (int nt = 0; nt < 4; ++nt) {
        f16x8 bv = *reinterpret_cast<const f16x8*>(
            &Vts[(nt * 16 + lr) * 72 + ks * 32 + qd * 8]);
        o_acc[0][nt] = __builtin_amdgcn_mfma_f32_16x16x32_f16(
            ap[0], bv, o_acc[0][nt], 0, 0, 0);
        o_acc[1][nt] = __builtin_amdgcn_mfma_f32_16x16x32_f16(
            ap[1], bv, o_acc[1][nt], 0, 0, 0);
      }
    }
  }

#pragma unroll
  for (int rt = 0; rt < 2; ++rt)
#pragma unroll
    for (int r = 0; r < 4; ++r) {
#pragma unroll
      for (int m = 1; m < 16; m <<= 1)
        lsum[rt][r] += __shfl_xor(lsum[rt][r], m, 64);
    }

#pragma unroll
  for (int rt = 0; rt < 2; ++rt) {
#pragma unroll
    for (int nt = 0; nt < 4; ++nt) {
#pragma unroll
      for (int r = 0; r < 4; ++r) {
        int qr = q0 + w * 32 + rt * 16 + qd * 4 + r;
        if (qr < kL) {
          attnout[(size_t)(b * kL + qr) * kC + h * kD + nt * 16 + lr] =
              (f16)(o_acc[rt][nt][r] / lsum[rt][r]);
        }
      }
    }
  }
}

}  // namespace

extern "C" void kernel_launch(void* const* d_in, const int* in_sizes, int n_in,
                              void* d_out, int out_size, void* d_ws,
                              size_t ws_size, hipStream_t stream) {
  const float* x = (const float*)d_in[0];
  const float* pos = (const float*)d_in[1];
  const float* w_qkv = (const float*)d_in[2];
  const float* q_bias = (const float*)d_in[3];
  const float* v_bias = (const float*)d_in[4];
  const float* w_o = (const float*)d_in[5];
  const float* b_o = (const float*)d_in[6];
  float* out = (float*)d_out;

  f16* qkv16 = (f16*)d_ws;                       // kM*kN3
  f16* x16 = qkv16 + (size_t)kM * kN3;           // kM*kC
  f16* wqkv16 = x16 + (size_t)kM * kC;           // kN3*kC
  f16* wo16 = wqkv16 + (size_t)kN3 * kC;         // kC*kC
  f16* ao16 = wo16 + (size_t)kC * kC;            // kM*kC
  float* bias_full = (float*)(ao16 + (size_t)kM * kC);  // kN3 floats

  {
    const int c0 = kM * kC / 4, c1 = kN3 * kC / 4, c2 = kC * kC / 4,
              c3 = kN3 / 4;
    int nchunks = c0 + c1 + c2 + c3;
    fused_cvt_bias<<<(nchunks + 255) / 256, 256, 0, stream>>>(
        x, w_qkv, w_o, q_bias, v_bias, x16, wqkv16, wo16, bias_full);
  }
  gemm256_8ph<f16, true><<<dim3(kN3 / 256, (kM + 255) / 256), 512, 0,
                           stream>>>(x16, wqkv16, bias_full, qkv16, pos, kM,
                                     kN3, kC, 0);
  attn_mfma<<<dim3(kNQT * kH * kB), 256, 0, stream>>>(qkv16, ao16);
  gemm256_8ph<float, false><<<dim3(kC / 256, (kM + 255) / 256), 512, 0,
                              stream>>>(ao16, wo16, b_o, out, nullptr, kM, kC,
                                        kC, 0);
}

// Round 11
// 339.657 us; speedup vs baseline: 1.1113x; 1.1113x over previous
//
#include <hip/hip_runtime.h>
#include <cmath>

typedef _Float16 f16;
typedef _Float16 f16x2 __attribute__((ext_vector_type(2)));
typedef _Float16 f16x4 __attribute__((ext_vector_type(4)));
typedef _Float16 f16x8 __attribute__((ext_vector_type(8)));
typedef float f32x4 __attribute__((ext_vector_type(4)));

namespace {

constexpr int kB = 8;
constexpr int kL = 680;
constexpr int kH = 24;
constexpr int kD = 64;
constexpr int kC = 1536;          // kH * kD
constexpr int kM = kB * kL;       // 5440
constexpr int kN3 = 3 * kC;       // 4608
constexpr int kNKT = 11;          // ceil(680/64)
constexpr int kNQT = 6;           // ceil(680/128)

#define ASYNC_CP16(gp, lp)                                          \
  __builtin_amdgcn_global_load_lds(                                 \
      (const __attribute__((address_space(1))) unsigned int*)(gp),  \
      (__attribute__((address_space(3))) unsigned int*)(lp), 16, 0, 0)

// Bijective XCD swizzle (m204).
__device__ inline int xcd_swizzle(int bid, int nwg) {
  int q = nwg >> 3, r = nwg & 7;
  int x = bid & 7, idx = bid >> 3;
  return (x < r ? x * (q + 1) : r * (q + 1) + (x - r) * q) + idx;
}

// 4-wide n-stripe decode (with xcd_swizzle: FETCH 122.9 -> 74.3 MB, r6).
__device__ inline void stripe_decode(int id, int gx, int gy, int& mt,
                                     int& nt) {
  const int SW = 4;
  int nst = (gx + SW - 1) / SW;
  int s = id / (gy * SW);
  if (s > nst - 1) s = nst - 1;
  int rem = id - s * gy * SW;
  int w = gx - s * SW;
  if (w > SW) w = SW;
  mt = rem / w;
  nt = s * SW + rem % w;
}

// ------------------------- fused fp32->fp16 conversions + bias build
__global__ void fused_cvt_bias(const float* __restrict__ x,
                               const float* __restrict__ wqkv,
                               const float* __restrict__ wo,
                               const float* __restrict__ qb,
                               const float* __restrict__ vb,
                               f16* __restrict__ x16,
                               f16* __restrict__ wqkv16,
                               f16* __restrict__ wo16,
                               float* __restrict__ bias) {
  const int c0 = kM * kC / 4, c1 = kN3 * kC / 4, c2 = kC * kC / 4,
            c3 = kN3 / 4;
  int i = blockIdx.x * blockDim.x + threadIdx.x;
  const float* src = nullptr;
  f16* dst = nullptr;
  if (i < c0) {
    src = x; dst = x16;
  } else if ((i -= c0) < c1) {
    src = wqkv; dst = wqkv16;
  } else if ((i -= c1) < c2) {
    src = wo; dst = wo16;
  } else if ((i -= c2) < c3) {
    int base = i * 4;
    float vv[4];
#pragma unroll
    for (int k2 = 0; k2 < 4; ++k2) {
      int idx = base + k2;
      float b = 0.0f;
      if (idx < kC) b = qb[idx];
      else if (idx >= 2 * kC) b = vb[idx - 2 * kC];
      vv[k2] = b;
    }
    *reinterpret_cast<float4*>(&bias[base]) =
        make_float4(vv[0], vv[1], vv[2], vv[3]);
    return;
  } else {
    return;
  }
  float4 v = *reinterpret_cast<const float4*>(&src[i * 4]);
  f16x4 o;
  o[0] = (f16)v.x; o[1] = (f16)v.y; o[2] = (f16)v.z; o[3] = (f16)v.w;
  *reinterpret_cast<f16x4*>(&dst[i * 4]) = o;
}

// ----------------------------------- v15: 8-phase GEMM, COALESCED staging
// v14 -> v15: LDS half-tiles become row-major [128r][8 x 16B cols] with the
// XOR involution col' = col ^ (row&7) (T2 + m173: linear LDS dst,
// pre-swizzled GLOBAL source, swizzled ds_read -- rule #21 both-sides).
// Why: the old k-major-blocked layout made each staging wave load 64
// different rows at 3KB stride = 64 scattered 16B L2 requests/instruction;
// 1024 requests per phase per CU ~= the ~1000 cyc/phase unexplained residual
// vs m201's 822 cyc/phase (TA address-pipe serialization, waited on by the
// vmcnt gate). New source pattern: 8 rows x contiguous 128B per wave -> 4x
// fewer requests. Bank distribution of fragment reads is IDENTICAL to the
// old layout (byte = row*128 + col'*16; row stride = exactly 32 banks), so
// the LDS side is provably neutral -- measured 0 conflicts before.
// Schedule (stage slots, vmcnt gates, phases) byte-identical to v10/v14.
template <typename OutT, bool ROPE>
__global__ __launch_bounds__(512, 2) void gemm256_8ph(
    const f16* __restrict__ A, const f16* __restrict__ Bw,
    const float* __restrict__ bias, OutT* __restrict__ Cm,
    const float* __restrict__ pos, int M, int N, int K, int n_base) {
  constexpr int HALF = 8192;      // f16 per half-tile (128 rows x 64 k)
  constexpr int ABUF = 2 * HALF;  // 16384 f16
  constexpr int BUF = 2 * ABUF;   // 32768 f16: [A h0|A h1|B h0|B h1]
  __shared__ __align__(16) f16 sm[2 * BUF];  // 128 KB

  const int tid = threadIdx.x;
  const int w = tid >> 6;
  const int lane = tid & 63;
  const int lr = lane & 15;
  const int quad = lane >> 4;
  const int wr = w >> 2;   // 0..1 : which 128-row half this wave computes
  const int wc = w & 3;    // 0..3 : which 64-col quarter
  const int gx = gridDim.x;
  const int sw = xcd_swizzle(blockIdx.y * gx + blockIdx.x, gx * gridDim.y);
  int mt, nt;
  stripe_decode(sw, gx, gridDim.y, mt, nt);
  const int m0 = mt * 256;
  const int n0 = n_base + nt * 256;
  const int NT = K >> 6;   // 24 (even)

  // Staging descriptors, row-major + source pre-swizzle.
  // LDS 16B-block d = n*512+tid -> row r = d>>3, col c = d&7 (linear dst).
  // Source col = c ^ (r&7): per wave, 8 rows x full contiguous 128B.
  const f16* aptr[2][2];  // [half][n]
  const f16* bptr[2][2];
  int dstoff0 = tid * 8;
  int dstoff1 = (tid + 512) * 8;
#pragma unroll
  for (int h = 0; h < 2; ++h) {
#pragma unroll
    for (int n = 0; n < 2; ++n) {
      int d = n * 512 + tid;
      int r = d >> 3, c = d & 7;
      int sc = (c ^ (r & 7)) * 8;
      int ra = m0 + h * 128 + r;
      if (ra > M - 1) ra = M - 1;  // duplicate last rows; stores masked
      aptr[h][n] = A + (size_t)ra * K + sc;
      bptr[h][n] = Bw + (size_t)(n0 + h * 128 + r) * K + sc;  // N%256==0
    }
  }

  auto stageA = [&](int t, int h, int q) {
    f16* d = &sm[q * BUF + h * HALF];
    ASYNC_CP16(aptr[h][0] + t * 64, &d[dstoff0]);
    ASYNC_CP16(aptr[h][1] + t * 64, &d[dstoff1]);
  };
  auto stageB = [&](int t, int h, int q) {
    f16* d = &sm[q * BUF + ABUF + h * HALF];
    ASYNC_CP16(bptr[h][0] + t * 64, &d[dstoff0]);
    ASYNC_CP16(bptr[h][1] + t * 64, &d[dstoff1]);
  };

  f32x4 acc[8][4];
#pragma unroll
  for (int i = 0; i < 8; ++i)
#pragma unroll
    for (int j = 0; j < 4; ++j)
#pragma unroll
      for (int c = 0; c < 4; ++c) acc[i][j][c] = 0.0f;

  const int bRow0 = (wc & 1) * 64;  // row offset within B half-tile
  const int lr7 = lr & 7;
  const int cq0 = quad ^ lr7;        // swizzled col for k-slice s=0
  const int cq1 = (4 + quad) ^ lr7;  // swizzled col for k-slice s=1

  // Prologue: tile0 (4 halves) + B(1) halves = 12 loads; vmcnt(4) leaves
  // B(1)'s 4 in flight and guarantees tile0 landed. A(1) comes at P1/P2.
  stageA(0, 0, 0);
  stageA(0, 1, 0);
  stageB(0, 0, 0);
  stageB(0, 1, 0);
  stageB(1, 0, 1);
  stageB(1, 1, 1);
  asm volatile("s_waitcnt vmcnt(4)" ::: "memory");
  __builtin_amdgcn_s_barrier();

  const int NIT = NT >> 1;
  for (int itr = 0; itr < NIT; ++itr) {
    const int t0 = itr * 2;
#pragma unroll
    for (int hf = 0; hf < 2; ++hf) {
      const int tcur = t0 + hf;      // consumed tile, buffer = hf
      const int ta = tcur + 1;       // A prefetch target -> buf hf^1
      const int tb = tcur + 2;       // B prefetch target -> buf hf
      const f16* Aq = &sm[hf * BUF + wr * HALF];
      const f16* Bq = &sm[hf * BUF + ABUF + (wc >> 1) * HALF];
      f16x8 a0[4], a1[4], b0[4], b1[4];

      // ---- P1 (8 reads): A s0 i0-3 + B s0 j0-3; stage Ah0(ta)
#pragma unroll
      for (int i = 0; i < 4; ++i)
        a0[i] = *reinterpret_cast<const f16x8*>(
            &Aq[((i * 16 + lr) * 8 + cq0) * 8]);
#pragma unroll
      for (int j = 0; j < 4; ++j)
        b0[j] = *reinterpret_cast<const f16x8*>(
            &Bq[((bRow0 + j * 16 + lr) * 8 + cq0) * 8]);
      if (ta < NT) stageA(ta, 0, hf ^ 1);
      __builtin_amdgcn_s_barrier();
      asm volatile("s_waitcnt lgkmcnt(0)" ::: "memory");
      __builtin_amdgcn_s_setprio(1);
#pragma unroll
      for (int i = 0; i < 4; ++i)
#pragma unroll
        for (int j = 0; j < 4; ++j)
          acc[i][j] = __builtin_amdgcn_mfma_f32_16x16x32_f16(
              a0[i], b0[j], acc[i][j], 0, 0, 0);
      __builtin_amdgcn_s_setprio(0);
      __builtin_amdgcn_s_barrier();

      // ---- P2 (8 reads): B s1 j0-3 + A s0 i4-7; stage Ah1(ta)
#pragma unroll
      for (int j = 0; j < 4; ++j)
        b1[j] = *reinterpret_cast<const f16x8*>(
            &Bq[((bRow0 + j * 16 + lr) * 8 + cq1) * 8]);
#pragma unroll
      for (int i = 0; i < 4; ++i)
        a1[i] = *reinterpret_cast<const f16x8*>(
            &Aq[(((i + 4) * 16 + lr) * 8 + cq0) * 8]);
      if (ta < NT) stageA(ta, 1, hf ^ 1);
      __builtin_amdgcn_s_barrier();
      asm volatile("s_waitcnt lgkmcnt(0)" ::: "memory");
      __builtin_amdgcn_s_setprio(1);
#pragma unroll
      for (int i = 0; i < 4; ++i)
#pragma unroll
        for (int j = 0; j < 4; ++j)
          acc[i + 4][j] = __builtin_amdgcn_mfma_f32_16x16x32_f16(
              a1[i], b0[j], acc[i + 4][j], 0, 0, 0);
      __builtin_amdgcn_s_setprio(0);
      __builtin_amdgcn_s_barrier();

      // ---- P3 (4 reads): A s1 i0-3; stage Bh0(tb)
#pragma unroll
      for (int i = 0; i < 4; ++i)
        a0[i] = *reinterpret_cast<const f16x8*>(
            &Aq[((i * 16 + lr) * 8 + cq1) * 8]);
      if (tb < NT) stageB(tb, 0, hf);
      __builtin_amdgcn_s_barrier();
      asm volatile("s_waitcnt lgkmcnt(0)" ::: "memory");
      __builtin_amdgcn_s_setprio(1);
#pragma unroll
      for (int i = 0; i < 4; ++i)
#pragma unroll
        for (int j = 0; j < 4; ++j)
          acc[i][j] = __builtin_amdgcn_mfma_f32_16x16x32_f16(
              a0[i], b1[j], acc[i][j], 0, 0, 0);
      __builtin_amdgcn_s_setprio(0);
      __builtin_amdgcn_s_barrier();

      // ---- P4 (4 reads): A s1 i4-7; stage Bh1(tb); gate
#pragma unroll
      for (int i = 0; i < 4; ++i)
        a1[i] = *reinterpret_cast<const f16x8*>(
            &Aq[(((i + 4) * 16 + lr) * 8 + cq1) * 8]);
      if (tb < NT) stageB(tb, 1, hf);
      __builtin_amdgcn_s_barrier();
      asm volatile("s_waitcnt lgkmcnt(0)" ::: "memory");
      __builtin_amdgcn_s_setprio(1);
#pragma unroll
      for (int i = 0; i < 4; ++i)
#pragma unroll
        for (int j = 0; j < 4; ++j)
          acc[i + 4][j] = __builtin_amdgcn_mfma_f32_16x16x32_f16(
              a1[i], b1[j], acc[i + 4][j], 0, 0, 0);
      __builtin_amdgcn_s_setprio(0);
      if (tb < NT)
        asm volatile("s_waitcnt vmcnt(4)" ::: "memory");
      else
        asm volatile("s_waitcnt vmcnt(0)" ::: "memory");
      __builtin_amdgcn_s_barrier();
    }
  }

  // Epilogue: C/D layout col = lane&15, row = quad*4+reg.
  float bv[4];
#pragma unroll
  for (int j = 0; j < 4; ++j) bv[j] = bias[n0 + wc * 64 + j * 16 + lr];

  if (ROPE && n0 < 2 * kC) {
    // 2D RoPE on a Q or K block (native __sinf/__cosf: no scratch, r5 fix).
    const float fr = exp2f(-(float)lr * (13.287712379549449f / 16.0f));
#pragma unroll
    for (int i = 0; i < 8; ++i) {
#pragma unroll
      for (int r = 0; r < 4; ++r) {
        int row = m0 + wr * 128 + i * 16 + quad * 4 + r;
        if (row < M) {
          float a0r = pos[row * 2 + 0] * fr;
          float a1r = pos[row * 2 + 1] * fr;
          float s0 = __sinf(a0r), c0 = __cosf(a0r);
          float s1 = __sinf(a1r), c1 = __cosf(a1r);
#pragma unroll
          for (int j = 0; j < 2; ++j) {
            float v0 = acc[i][j][r] + bv[j];
            float v1 = acc[i][j + 2][r] + bv[j + 2];
            int col = n0 + wc * 64 + j * 16 + lr;
            Cm[(size_t)row * N + col] = (OutT)(v0 * c0 - v1 * s0);
            Cm[(size_t)row * N + col + 32] = (OutT)(v1 * c1 + v0 * s1);
          }
        }
      }
    }
  } else {
#pragma unroll
    for (int i = 0; i < 8; ++i) {
#pragma unroll
      for (int j = 0; j < 4; ++j) {
#pragma unroll
        for (int r = 0; r < 4; ++r) {
          int row = m0 + wr * 128 + i * 16 + quad * 4 + r;
          if (row < M) {
            int col = n0 + wc * 64 + j * 16 + lr;
            Cm[(size_t)row * N + col] = (OutT)(acc[i][j][r] + bv[j]);
          }
        }
      }
    }
  }
}

// ----------------------------------------------------- MFMA flash attention
// (v14: f16 P in LDS, 1/8 scale folded into Q, launch_bounds(256,4))
__global__ __launch_bounds__(256, 4) void attn_mfma(
    const f16* __restrict__ qkv, f16* __restrict__ attnout) {
  __shared__ __align__(16) f16 Ks[64 * 72];       // [key][d]
  __shared__ __align__(16) f16 Vts[64 * 72];      // [d][key]  (V transposed)
  __shared__ __align__(16) f16 Pl[4][32 * 72];    // per-wave [qrow][key] f16

  const int tid = threadIdx.x;
  const int w = tid >> 6;
  const int lane = tid & 63;
  const int lr = lane & 15;
  const int qd = lane >> 4;

  const int bid = blockIdx.x;
  const int xcd = bid & 7;
  const int rest = bid >> 3;
  const int qt = rest % kNQT;
  const int g = xcd + 8 * (rest / kNQT);
  const int h = g % kH;
  const int b = g / kH;
  const int q0 = qt * 128;

  f16x8 aq[2][2];
#pragma unroll
  for (int rt = 0; rt < 2; ++rt) {
    int qrow = q0 + w * 32 + rt * 16 + lr;
    if (qrow > kL - 1) qrow = kL - 1;
    const f16* qp = qkv + (size_t)(b * kL + qrow) * kN3 + h * kD;
#pragma unroll
    for (int ks = 0; ks < 2; ++ks) {
      f16x8 qv = *reinterpret_cast<const f16x8*>(qp + ks * 32 + qd * 8);
#pragma unroll
      for (int e = 0; e < 8; ++e) qv[e] = qv[e] * (f16)0.125f;
      aq[rt][ks] = qv;
    }
  }

  const int kkey0 = tid >> 3, kdc = tid & 7;
  const int kkey1 = (tid + 256) >> 3;
  const int vkey0 = (tid & 31) * 2;
  const int vd0 = (tid >> 5) * 8;

  f16x8 kpre0, kpre1, vpre0, vpre1;
  auto prefetch = [&](int kt0) {
    int kg0 = kt0 + kkey0;
    if (kg0 > kL - 1) kg0 = kL - 1;
    kpre0 = *reinterpret_cast<const f16x8*>(
        qkv + (size_t)(b * kL + kg0) * kN3 + kC + h * kD + kdc * 8);
    int kg1 = kt0 + kkey1;
    if (kg1 > kL - 1) kg1 = kL - 1;
    kpre1 = *reinterpret_cast<const f16x8*>(
        qkv + (size_t)(b * kL + kg1) * kN3 + kC + h * kD + kdc * 8);
    int vg0 = kt0 + vkey0;
    if (vg0 > kL - 1) vg0 = kL - 1;
    vpre0 = *reinterpret_cast<const f16x8*>(
        qkv + (size_t)(b * kL + vg0) * kN3 + 2 * kC + h * kD + vd0);
    int vg1 = kt0 + vkey0 + 1;
    if (vg1 > kL - 1) vg1 = kL - 1;
    vpre1 = *reinterpret_cast<const f16x8*>(
        qkv + (size_t)(b * kL + vg1) * kN3 + 2 * kC + h * kD + vd0);
  };
  prefetch(0);

  f32x4 o_acc[2][4];
#pragma unroll
  for (int rt = 0; rt < 2; ++rt)
#pragma unroll
    for (int nt = 0; nt < 4; ++nt)
#pragma unroll
      for (int r = 0; r < 4; ++r) o_acc[rt][nt][r] = 0.0f;
  float lsum[2][4] = {{0.f, 0.f, 0.f, 0.f}, {0.f, 0.f, 0.f, 0.f}};

  for (int it = 0; it < kNKT; ++it) {
    const int kt0 = it * 64;
    __syncthreads();

    *reinterpret_cast<f16x8*>(&Ks[kkey0 * 72 + kdc * 8]) = kpre0;
    *reinterpret_cast<f16x8*>(&Ks[kkey1 * 72 + kdc * 8]) = kpre1;
#pragma unroll
    for (int i = 0; i < 8; ++i) {
      f16x2 pr;
      pr[0] = vpre0[i];
      pr[1] = vpre1[i];
      *reinterpret_cast<f16x2*>(&Vts[(vd0 + i) * 72 + vkey0]) = pr;
    }
    prefetch((it < kNKT - 1) ? (it + 1) * 64 : it * 64);
    __syncthreads();

    f32x4 s_acc[2][4];
#pragma unroll
    for (int rt = 0; rt < 2; ++rt)
#pragma unroll
      for (int t = 0; t < 4; ++t)
#pragma unroll
        for (int r = 0; r < 4; ++r) s_acc[rt][t][r] = 0.0f;
#pragma unroll
    for (int ks = 0; ks < 2; ++ks) {
#pragma unroll
      for (int t = 0; t < 4; ++t) {
        f16x8 bk = *reinterpret_cast<const f16x8*>(
            &Ks[(t * 16 + lr) * 72 + ks * 32 + qd * 8]);
        s_acc[0][t] = __builtin_amdgcn_mfma_f32_16x16x32_f16(
            aq[0][ks], bk, s_acc[0][t], 0, 0, 0);
        s_acc[1][t] = __builtin_amdgcn_mfma_f32_16x16x32_f16(
            aq[1][ks], bk, s_acc[1][t], 0, 0, 0);
      }
    }

#pragma unroll
    for (int rt = 0; rt < 2; ++rt) {
#pragma unroll
      for (int t = 0; t < 4; ++t) {
        const bool valid = (kt0 + t * 16 + lr) < kL;
#pragma unroll
        for (int r = 0; r < 4; ++r) {
          float p = valid ? __expf(s_acc[rt][t][r]) : 0.0f;
          lsum[rt][r] += p;
          Pl[w][(rt * 16 + qd * 4 + r) * 72 + t * 16 + lr] = (f16)p;
        }
      }
    }

#pragma unroll
    for (int ks = 0; ks < 2; ++ks) {
      f16x8 ap[2];
#pragma unroll
      for (int rt = 0; rt < 2; ++rt)
        ap[rt] = *reinterpret_cast<const f16x8*>(
            &Pl[w][(rt * 16 + lr) * 72 + ks * 32 + qd * 8]);
#pragma unroll
      for (int nt = 0; nt < 4; ++nt) {
        f16x8 bv = *reinterpret_cast<const f16x8*>(
            &Vts[(nt * 16 + lr) * 72 + ks * 32 + qd * 8]);
        o_acc[0][nt] = __builtin_amdgcn_mfma_f32_16x16x32_f16(
            ap[0], bv, o_acc[0][nt], 0, 0, 0);
        o_acc[1][nt] = __builtin_amdgcn_mfma_f32_16x16x32_f16(
            ap[1], bv, o_acc[1][nt], 0, 0, 0);
      }
    }
  }

#pragma unroll
  for (int rt = 0; rt < 2; ++rt)
#pragma unroll
    for (int r = 0; r < 4; ++r) {
#pragma unroll
      for (int m = 1; m < 16; m <<= 1)
        lsum[rt][r] += __shfl_xor(lsum[rt][r], m, 64);
    }

#pragma unroll
  for (int rt = 0; rt < 2; ++rt) {
#pragma unroll
    for (int nt = 0; nt < 4; ++nt) {
#pragma unroll
      for (int r = 0; r < 4; ++r) {
        int qr = q0 + w * 32 + rt * 16 + qd * 4 + r;
        if (qr < kL) {
          attnout[(size_t)(b * kL + qr) * kC + h * kD + nt * 16 + lr] =
              (f16)(o_acc[rt][nt][r] / lsum[rt][r]);
        }
      }
    }
  }
}

}  // namespace

extern "C" void kernel_launch(void* const* d_in, const int* in_sizes, int n_in,
                              void* d_out, int out_size, void* d_ws,
                              size_t ws_size, hipStream_t stream) {
  const float* x = (const float*)d_in[0];
  const float* pos = (const float*)d_in[1];
  const float* w_qkv = (const float*)d_in[2];
  const float* q_bias = (const float*)d_in[3];
  const float* v_bias = (const float*)d_in[4];
  const float* w_o = (const float*)d_in[5];
  const float* b_o = (const float*)d_in[6];
  float* out = (float*)d_out;

  f16* qkv16 = (f16*)d_ws;                       // kM*kN3
  f16* x16 = qkv16 + (size_t)kM * kN3;           // kM*kC
  f16* wqkv16 = x16 + (size_t)kM * kC;           // kN3*kC
  f16* wo16 = wqkv16 + (size_t)kN3 * kC;         // kC*kC
  f16* ao16 = wo16 + (size_t)kC * kC;            // kM*kC
  float* bias_full = (float*)(ao16 + (size_t)kM * kC);  // kN3 floats

  {
    const int c0 = kM * kC / 4, c1 = kN3 * kC / 4, c2 = kC * kC / 4,
              c3 = kN3 / 4;
    int nchunks = c0 + c1 + c2 + c3;
    fused_cvt_bias<<<(nchunks + 255) / 256, 256, 0, stream>>>(
        x, w_qkv, w_o, q_bias, v_bias, x16, wqkv16, wo16, bias_full);
  }
  gemm256_8ph<f16, true><<<dim3(kN3 / 256, (kM + 255) / 256), 512, 0,
                           stream>>>(x16, wqkv16, bias_full, qkv16, pos, kM,
                                     kN3, kC, 0);
  attn_mfma<<<dim3(kNQT * kH * kB), 256, 0, stream>>>(qkv16, ao16);
  gemm256_8ph<float, false><<<dim3(kC / 256, (kM + 255) / 256), 512, 0,
                              stream>>>(ao16, wo16, b_o, out, nullptr, kM, kC,
                                        kC, 0);
}